// Round 15
// baseline (157.316 us; speedup 1.0000x reference)
//
#include <hip/hip_runtime.h>
#include <hip/hip_bf16.h>

// SparseLinear forward as DENSE bf16 MFMA GEMM:  C = A * B^T + bias (4096^3).
// R15 = R14's lean-sync structure (ONE counted vmcnt + ONE barrier per K-tile,
// A 2-deep + B 3-deep LDS rings, 160 KiB) with MFMA shape 32x32x16:
// same LDS traffic, half the MFMA instruction count, MFMA wall -17%
// (2382 vs 2075 TF ubench). Clean A/B vs R14: only fragment addressing,
// MFMA shape, and epilogue differ. Ledger: per tile issue A(t+1) then
// B(t+2); entry vmcnt(4) retains exactly B(t+1); prologue B(0),A(0),B(1);
// final tile vmcnt(0). Zero-conflict granule-XOR swizzle (same staging),
// register-held B (8 x bf16x8), setprio, fused-bias epilogue.

typedef __bf16 bf16x8 __attribute__((ext_vector_type(8)));
typedef float f32x16 __attribute__((ext_vector_type(16)));

constexpr int M = 4096;   // T*B
constexpr int N = 4096;   // C_OUT
constexpr int K = 4096;   // C_IN
constexpr int BM = 256, BN = 256, BK = 64;
constexpr int NT = K / BK;          // 64 K-tiles
constexpr int A_BUF = 16384;        // elems per A buffer (2 units: k0,k1)
constexpr int B_BASE = 32768;       // elem offset of B region
constexpr int B_SLOT = 16384;       // elems per B slot (2 units: k0,k1)

__device__ __forceinline__ unsigned short f2bf_rne(float f) {
    unsigned int u = __float_as_uint(f);
    u += 0x7fffu + ((u >> 16) & 1u);   // round-to-nearest-even
    return (unsigned short)(u >> 16);
}

// Fused convert: x -> Abf and w -> Bbf in one launch.
__global__ __launch_bounds__(256) void cvt_both(const float* __restrict__ x,
                                                const float* __restrict__ w,
                                                unsigned short* __restrict__ Abf,
                                                unsigned short* __restrict__ Bbf) {
    const int n8 = (M * K) / 8;
    int idx = blockIdx.x * blockDim.x + threadIdx.x;
    int stride = gridDim.x * blockDim.x;
    for (int i = idx; i < 2 * n8; i += stride) {
        const float* src;
        unsigned short* dst;
        if (i < n8) { long b = (long)i * 8;        src = x + b; dst = Abf + b; }
        else        { long b = (long)(i - n8) * 8; src = w + b; dst = Bbf + b; }
        float4 v0 = *(const float4*)(src);
        float4 v1 = *(const float4*)(src + 4);
        ushort4 r0, r1;
        r0.x = f2bf_rne(v0.x); r0.y = f2bf_rne(v0.y);
        r0.z = f2bf_rne(v0.z); r0.w = f2bf_rne(v0.w);
        r1.x = f2bf_rne(v1.x); r1.y = f2bf_rne(v1.y);
        r1.z = f2bf_rne(v1.z); r1.w = f2bf_rne(v1.w);
        *(ushort4*)(dst) = r0;
        *(ushort4*)(dst + 4) = r1;
    }
}

// Stage one k-half unit ([256 rows][32 k] = 16 KiB, 2 global_load_lds) into
// LDS (linear dest, pre-swizzled global source: cg ^= (row>>1)&3).
__device__ __forceinline__ void stage_unit(const unsigned short* __restrict__ g,
                                           size_t grow0, int kcol0,
                                           unsigned short* unitbase,
                                           int tid, int wave) {
#pragma unroll
    for (int i = 0; i < 2; ++i) {
        const int row = i * 128 + (tid >> 2);
        const int cg  = (tid & 3) ^ ((row >> 1) & 3);
        const unsigned short* src = g + (grow0 + (size_t)row) * (size_t)K
                                      + (size_t)(kcol0 + cg * 8);
        unsigned short* dst = unitbase + i * 4096 + wave * 512;
        __builtin_amdgcn_global_load_lds(
            (const __attribute__((address_space(1))) void*)src,
            (__attribute__((address_space(3))) void*)dst, 16, 0, 0);
    }
}

// One m-frag phase (32 rows): 4 A-reads (k-steps s=0..3) x held b[2][4],
// 8 MFMA 32x32x16 (two independent 4-chains).
#define PHASE32(MI)                                                            \
    {                                                                          \
        bf16x8 a0 = *(const bf16x8*)(aB + (MI) * 1024 + koffA0);               \
        bf16x8 a1 = *(const bf16x8*)(aB + (MI) * 1024 + koffA1);               \
        bf16x8 a2 = *(const bf16x8*)(aB + (MI) * 1024 + 8192 + koffA0);        \
        bf16x8 a3 = *(const bf16x8*)(aB + (MI) * 1024 + 8192 + koffA1);        \
        __builtin_amdgcn_s_setprio(1);                                         \
        acc[MI][0] = __builtin_amdgcn_mfma_f32_32x32x16_bf16(                  \
            a0, b[0][0], acc[MI][0], 0, 0, 0);                                 \
        acc[MI][1] = __builtin_amdgcn_mfma_f32_32x32x16_bf16(                  \
            a0, b[1][0], acc[MI][1], 0, 0, 0);                                 \
        acc[MI][0] = __builtin_amdgcn_mfma_f32_32x32x16_bf16(                  \
            a1, b[0][1], acc[MI][0], 0, 0, 0);                                 \
        acc[MI][1] = __builtin_amdgcn_mfma_f32_32x32x16_bf16(                  \
            a1, b[1][1], acc[MI][1], 0, 0, 0);                                 \
        acc[MI][0] = __builtin_amdgcn_mfma_f32_32x32x16_bf16(                  \
            a2, b[0][2], acc[MI][0], 0, 0, 0);                                 \
        acc[MI][1] = __builtin_amdgcn_mfma_f32_32x32x16_bf16(                  \
            a2, b[1][2], acc[MI][1], 0, 0, 0);                                 \
        acc[MI][0] = __builtin_amdgcn_mfma_f32_32x32x16_bf16(                  \
            a3, b[0][3], acc[MI][0], 0, 0, 0);                                 \
        acc[MI][1] = __builtin_amdgcn_mfma_f32_32x32x16_bf16(                  \
            a3, b[1][3], acc[MI][1], 0, 0, 0);                                 \
        __builtin_amdgcn_s_setprio(0);                                        \
    }

__global__ __launch_bounds__(512, 2) void gemm_lean32(
    const unsigned short* __restrict__ A,   // [M][K] bf16 bits
    const unsigned short* __restrict__ B,   // [N][K] bf16 bits
    const float* __restrict__ bias,         // [N]
    float* __restrict__ C)                  // [M][N] fp32
{
    __shared__ unsigned short lds[81920];   // 160 KiB: A 2-deep + B 3-deep

    // XCD-aware bijective swizzle: 256 wgs, 256 % 8 == 0
    const int wg = blockIdx.x;
    const int s  = ((wg & 7) << 5) | (wg >> 3);
    const int bm = s >> 4, bn = s & 15;
    const size_t brow = (size_t)bm * BM;
    const size_t bcol = (size_t)bn * BN;

    const int tid  = threadIdx.x;
    const int wave = tid >> 6;
    const int lane = tid & 63;
    const int wr = wave >> 2;       // 0..1  (2 M-waves, 128 rows each)
    const int wc = wave & 3;        // 0..3  (4 N-waves, 64 cols each)
    const int l31 = lane & 31;      // 32-row fragment row
    const int hi  = lane >> 5;      // k-half within k-step

    // 32x32x16 fragment addressing within a [256][32] unit:
    // lane reads granule (2*sg + hi) of row (base + mi*32 + l31); swizzle
    // XOR ((row>>1)&3) is invariant under mi*32.
    const int arow = wr * 128 + l31;
    const int brw  = wc * 64 + l31;
    const int swa = (arow >> 1) & 3;
    const int swb = (brw >> 1) & 3;
    const int koffA0 = arow * 32 + (((0 + hi) ^ swa) << 3);   // sg=0
    const int koffA1 = arow * 32 + (((2 + hi) ^ swa) << 3);   // sg=1
    const int koffB0 = brw * 32 + (((0 + hi) ^ swb) << 3);
    const int koffB1 = brw * 32 + (((2 + hi) ^ swb) << 3);

    f32x16 acc[4][2];
#pragma unroll
    for (int mi = 0; mi < 4; ++mi)
#pragma unroll
        for (int ni = 0; ni < 2; ++ni)
#pragma unroll
            for (int r = 0; r < 16; ++r)
                acc[mi][ni][r] = 0.f;

    // ---- prologue: B(0), A(0), B(1) = 12 loads (B(1) newest) ----
    stage_unit(B, bcol, 0,       lds + B_BASE, tid, wave);
    stage_unit(B, bcol, 32,      lds + B_BASE + 8192, tid, wave);
    stage_unit(A, brow, 0,       lds, tid, wave);
    stage_unit(A, brow, 32,      lds + 8192, tid, wave);
    stage_unit(B, bcol, BK,      lds + B_BASE + B_SLOT, tid, wave);
    stage_unit(B, bcol, BK + 32, lds + B_BASE + B_SLOT + 8192, tid, wave);

    int bs = 0;   // B ring slot of tile t
    for (int t = 0; t < NT; ++t) {
        const bool pf1 = (t + 1) < NT;
        const bool pf2 = (t + 2) < NT;

        // Entry wait: A(t)+B(t) landed; B(t+1)'s 4 loads (newest) stay in
        // flight. Entry barrier fences all previous-tile LDS reads (WAR).
        if (pf1) { asm volatile("s_waitcnt vmcnt(4)" ::: "memory"); }
        else     { asm volatile("s_waitcnt vmcnt(0)" ::: "memory"); }
        __builtin_amdgcn_s_barrier();

        unsigned short* aB = lds + (t & 1) * A_BUF;          // compute A
        unsigned short* ao = lds + ((t & 1) ^ 1) * A_BUF;    // A stage target
        unsigned short* bb = lds + B_BASE + bs * B_SLOT;
        const int bs2 = (bs + 2 >= 3) ? bs - 1 : bs + 2;     // (t+2)%3
        unsigned short* b2 = lds + B_BASE + bs2 * B_SLOT;    // B stage target

        // ===== P1: load ALL B-frags (held whole tile) + m-frag 0 =====
        bf16x8 b[2][4];
#pragma unroll
        for (int ni = 0; ni < 2; ++ni) {
            b[ni][0] = *(const bf16x8*)(bb + ni * 1024 + koffB0);
            b[ni][1] = *(const bf16x8*)(bb + ni * 1024 + koffB1);
            b[ni][2] = *(const bf16x8*)(bb + ni * 1024 + 8192 + koffB0);
            b[ni][3] = *(const bf16x8*)(bb + ni * 1024 + 8192 + koffB1);
        }
        if (pf1) stage_unit(A, brow, (t + 1) * BK, ao, tid, wave);
        PHASE32(0)

        // ===== P2..P4: free-run (no barriers) =====
        if (pf1) stage_unit(A, brow, (t + 1) * BK + 32, ao + 8192, tid, wave);
        PHASE32(1)
        if (pf2) stage_unit(B, bcol, (t + 2) * BK, b2, tid, wave);
        PHASE32(2)
        if (pf2) stage_unit(B, bcol, (t + 2) * BK + 32, b2 + 8192, tid, wave);
        PHASE32(3)

        bs = (bs + 1 >= 3) ? 0 : bs + 1;
    }

    // ---- epilogue: 32x32 C/D layout (m74/m101, R8-verified): col = lane&31,
    //      row = (reg&3) + 8*(reg>>2) + 4*hi; fused bias ----
    float bsv[2];
#pragma unroll
    for (int ni = 0; ni < 2; ++ni)
        bsv[ni] = bias[bcol + wc * 64 + ni * 32 + l31];
    const size_t row00 = brow + (size_t)wr * 128 + 4 * hi;
#pragma unroll
    for (int mi = 0; mi < 4; ++mi) {
#pragma unroll
        for (int ni = 0; ni < 2; ++ni) {
            const size_t col = bcol + wc * 64 + ni * 32 + l31;
#pragma unroll
            for (int r = 0; r < 16; ++r) {
                const size_t row = row00 + mi * 32 + (r & 3) + 8 * (r >> 2);
                C[row * N + col] = acc[mi][ni][r] + bsv[ni];
            }
        }
    }
}

extern "C" void kernel_launch(void* const* d_in, const int* in_sizes, int n_in,
                              void* d_out, int out_size, void* d_ws, size_t ws_size,
                              hipStream_t stream) {
    const float* x    = (const float*)d_in[0];   // [T,B,C_IN] = [M,K]
    const float* w    = (const float*)d_in[1];   // [C_OUT,C_IN] = [N,K]
    const float* bias = (const float*)d_in[2];   // [N]
    float* out = (float*)d_out;                  // [M,N]

    unsigned short* Abf = (unsigned short*)d_ws;           // 32 MiB
    unsigned short* Bbf = Abf + (size_t)M * K;             // 32 MiB

    cvt_both<<<4096, 256, 0, stream>>>(x, w, Abf, Bbf);

    gemm_lean32<<<dim3((M / BM) * (N / BN)), 512, 0, stream>>>(Abf, Bbf, bias, out);
}

// Round 16
// 144.327 us; speedup vs baseline: 1.0900x; 1.0900x over previous
//
#include <hip/hip_runtime.h>
#include <hip/hip_bf16.h>

// SparseLinear forward: R14's lean-sync dense GEMM structure + PER-PANEL row
// compaction. Each 256-row A-panel is permuted (nonzero rows first) at prep;
// the GEMM keeps the dense 256-block grid / staging / vmcnt ledger / LDS
// layout and merely SKIPS fragment slots >= mfp = ceil(nonzero/16) via
// wave-uniform branches (interleaved frag ownership: wave wr owns frags
// wr+2m, balance +-1). Skipped slots store acc=0 + bias through the rowmap —
// exactly the right output for zero rows, so correctness is independent of
// mfp. Ledger (unchanged from R14): per tile issue A(t+1), B(t+2); entry
// vmcnt(4) retains exactly B(t+1); prologue B(0),A(0),B(1); tail vmcnt(0).
// A 2-deep + B 3-deep rings (160 KiB), zero-conflict granule-XOR swizzle,
// register-held B, setprio, rowmap-scatter fused-bias epilogue.

typedef __bf16 bf16x8 __attribute__((ext_vector_type(8)));
typedef float f32x4 __attribute__((ext_vector_type(4)));

constexpr int M = 4096;   // T*B
constexpr int N = 4096;   // C_OUT
constexpr int K = 4096;   // C_IN
constexpr int BM = 256, BN = 256, BK = 64;
constexpr int NT = K / BK;          // 64 K-tiles
constexpr int A_BUF = 16384;        // elems per A buffer (2 units: k0,k1)
constexpr int B_BASE = 32768;       // elem offset of B region
constexpr int B_SLOT = 16384;       // elems per B slot (2 units: k0,k1)

__device__ int g_front[16];         // per-panel nonzero-row count
__device__ int g_zc[16];            // per-panel zero-row count
__device__ int g_rowmap[M];         // panel-local slot -> original row

__device__ __forceinline__ unsigned short f2bf_rne(float f) {
    unsigned int u = __float_as_uint(f);
    u += 0x7fffu + ((u >> 16) & 1u);   // round-to-nearest-even
    return (unsigned short)(u >> 16);
}

__global__ void reset_k() {
    if (threadIdx.x < 16) { g_front[threadIdx.x] = 0; g_zc[threadIdx.x] = 0; }
}

// Blocks [0,4096): one x-row each — detect zero row, assign panel-local slot
// (nonzero -> front, zero -> back), record rowmap, convert to bf16 into the
// panel-compacted Abf. Blocks [4096,6144): grid-stride convert w -> Bbf.
__global__ __launch_bounds__(256) void prep(
    const float* __restrict__ x, const float* __restrict__ w,
    unsigned short* __restrict__ Abf, unsigned short* __restrict__ Bbf)
{
    const int tid = threadIdx.x;
    if (blockIdx.x < M) {
        const int row = blockIdx.x;
        const int p = row >> 8;
        const float4* xr = (const float4*)(x + (size_t)row * K);
        float4 v[4];
        bool nz = false;
#pragma unroll
        for (int i = 0; i < 4; ++i) {
            v[i] = xr[i * 256 + tid];
            nz = nz | (v[i].x != 0.f) | (v[i].y != 0.f) |
                      (v[i].z != 0.f) | (v[i].w != 0.f);
        }
        __shared__ int s_flag, s_pos;
        if (tid == 0) s_flag = 0;
        __syncthreads();
        if (nz) s_flag = 1;
        __syncthreads();
        if (tid == 0) {
            const int pos = s_flag ? atomicAdd(&g_front[p], 1)
                                   : 255 - atomicAdd(&g_zc[p], 1);
            g_rowmap[p * 256 + pos] = row;
            s_pos = pos;
        }
        __syncthreads();
        unsigned short* dst = Abf + (size_t)(p * 256 + s_pos) * K;
#pragma unroll
        for (int i = 0; i < 4; ++i) {
            ushort4 r;
            r.x = f2bf_rne(v[i].x); r.y = f2bf_rne(v[i].y);
            r.z = f2bf_rne(v[i].z); r.w = f2bf_rne(v[i].w);
            *(ushort4*)(dst + i * 1024 + tid * 4) = r;
        }
    } else {
        const int b = blockIdx.x - M;              // 0..2047
        const int n8 = (N * K) / 8;
        const int stride = 2048 * 256;
        for (int i = b * 256 + tid; i < n8; i += stride) {
            long base = (long)i * 8;
            float4 v0 = *(const float4*)(w + base);
            float4 v1 = *(const float4*)(w + base + 4);
            ushort4 r0, r1;
            r0.x = f2bf_rne(v0.x); r0.y = f2bf_rne(v0.y);
            r0.z = f2bf_rne(v0.z); r0.w = f2bf_rne(v0.w);
            r1.x = f2bf_rne(v1.x); r1.y = f2bf_rne(v1.y);
            r1.z = f2bf_rne(v1.z); r1.w = f2bf_rne(v1.w);
            *(ushort4*)(Bbf + base) = r0;
            *(ushort4*)(Bbf + base + 4) = r1;
        }
    }
}

// Stage one k-half unit ([256 rows][32 k] = 16 KiB, 2 global_load_lds) into
// LDS (linear dest, pre-swizzled global source: cg ^= (row>>1)&3).
__device__ __forceinline__ void stage_unit(const unsigned short* __restrict__ g,
                                           size_t grow0, int kcol0,
                                           unsigned short* unitbase,
                                           int tid, int wave) {
#pragma unroll
    for (int i = 0; i < 2; ++i) {
        const int row = i * 128 + (tid >> 2);
        const int cg  = (tid & 3) ^ ((row >> 1) & 3);
        const unsigned short* src = g + (grow0 + (size_t)row) * (size_t)K
                                      + (size_t)(kcol0 + cg * 8);
        unsigned short* dst = unitbase + i * 4096 + wave * 512;
        __builtin_amdgcn_global_load_lds(
            (const __attribute__((address_space(1))) void*)src,
            (__attribute__((address_space(3))) void*)dst, 16, 0, 0);
    }
}

// One fragment slot S (frag = wr + 2*S): 2 A-reads (k0,k1) x held b[4][2],
// 8 MFMA. Guard is wave-uniform; skipped slots keep acc=0 (epilogue then
// stores bias — correct for zero rows regardless of mfp).
#define SLOT(S)                                                                \
    if (wr + 2 * (S) < mfp) {                                                  \
        bf16x8 ak0 = *(const bf16x8*)(pA0 + (S) * 1024);                       \
        bf16x8 ak1 = *(const bf16x8*)(pA1 + (S) * 1024);                       \
        __builtin_amdgcn_s_setprio(1);                                         \
        _Pragma("unroll")                                                      \
        for (int n = 0; n < 4; ++n)                                            \
            acc[S][n] = __builtin_amdgcn_mfma_f32_16x16x32_bf16(               \
                ak0, b[n][0], acc[S][n], 0, 0, 0);                             \
        _Pragma("unroll")                                                      \
        for (int n = 0; n < 4; ++n)                                            \
            acc[S][n] = __builtin_amdgcn_mfma_f32_16x16x32_bf16(               \
                ak1, b[n][1], acc[S][n], 0, 0, 0);                             \
        __builtin_amdgcn_s_setprio(0);                                         \
    }

__global__ __launch_bounds__(512, 2) void gemm_skip(
    const unsigned short* __restrict__ A,   // [M][K] panel-compacted bf16
    const unsigned short* __restrict__ B,   // [N][K] bf16 bits
    const float* __restrict__ bias,         // [N]
    float* __restrict__ C)                  // [M][N] fp32 (rowmap scatter)
{
    __shared__ unsigned short lds[81920];   // 160 KiB: A 2-deep + B 3-deep

    // XCD-aware bijective swizzle: 256 wgs, 256 % 8 == 0
    const int wg = blockIdx.x;
    const int s  = ((wg & 7) << 5) | (wg >> 3);
    const int bm = s >> 4, bn = s & 15;
    const size_t brow = (size_t)bm * BM;
    const size_t bcol = (size_t)bn * BN;

    const int mfp = (*(volatile int*)&g_front[bm] + 15) >> 4;   // active frags

    const int tid  = threadIdx.x;
    const int wave = tid >> 6;
    const int lane = tid & 63;
    const int wr = wave >> 2;       // 0..1 : owns frags wr+2m (interleaved)
    const int wc = wave & 3;        // 0..3  (4 N-waves, 64 cols each)
    const int lr = lane & 15;       // fragment row-in-16
    const int kg = lane >> 4;       // k-group 0..3

    const int a_row0 = wr * 16 + lr;          // frag wr base rows
    const int b_row0 = wc * 64 + lr;
    const int aoff = a_row0 * 32 + ((kg ^ ((a_row0 >> 1) & 3)) << 3);
    const int boff = b_row0 * 32 + ((kg ^ ((b_row0 >> 1) & 3)) << 3);

    f32x4 acc[8][4];
#pragma unroll
    for (int m = 0; m < 8; ++m)
#pragma unroll
        for (int n = 0; n < 4; ++n)
            acc[m][n] = (f32x4){0.f, 0.f, 0.f, 0.f};

    // ---- prologue: B(0), A(0), B(1) = 12 loads (B(1) newest) ----
    stage_unit(B, bcol, 0,       lds + B_BASE, tid, wave);
    stage_unit(B, bcol, 32,      lds + B_BASE + 8192, tid, wave);
    stage_unit(A, brow, 0,       lds, tid, wave);
    stage_unit(A, brow, 32,      lds + 8192, tid, wave);
    stage_unit(B, bcol, BK,      lds + B_BASE + B_SLOT, tid, wave);
    stage_unit(B, bcol, BK + 32, lds + B_BASE + B_SLOT + 8192, tid, wave);

    int bs = 0;   // B ring slot of tile t
    for (int t = 0; t < NT; ++t) {
        const bool pf1 = (t + 1) < NT;
        const bool pf2 = (t + 2) < NT;

        // Entry wait: A(t)+B(t) landed; B(t+1)'s 4 loads stay in flight.
        if (pf1) { asm volatile("s_waitcnt vmcnt(4)" ::: "memory"); }
        else     { asm volatile("s_waitcnt vmcnt(0)" ::: "memory"); }
        __builtin_amdgcn_s_barrier();

        unsigned short* aB = lds + (t & 1) * A_BUF;
        unsigned short* ao = lds + ((t & 1) ^ 1) * A_BUF;    // A stage target
        unsigned short* bb = lds + B_BASE + bs * B_SLOT;
        const int bs2 = (bs + 2 >= 3) ? bs - 1 : bs + 2;     // (t+2)%3
        unsigned short* b2 = lds + B_BASE + bs2 * B_SLOT;    // B stage target

        const unsigned short* pA0 = aB + aoff;
        const unsigned short* pA1 = aB + 8192 + aoff;

        // ===== B-frags for whole tile (register-held) =====
        bf16x8 b[4][2];
#pragma unroll
        for (int n = 0; n < 4; ++n) {
            b[n][0] = *(const bf16x8*)(bb + boff + n * 512);
            b[n][1] = *(const bf16x8*)(bb + 8192 + boff + n * 512);
        }

        if (pf1) stage_unit(A, brow, (t + 1) * BK, ao, tid, wave);
        SLOT(0) SLOT(1)
        if (pf1) stage_unit(A, brow, (t + 1) * BK + 32, ao + 8192, tid, wave);
        SLOT(2) SLOT(3)
        if (pf2) stage_unit(B, bcol, (t + 2) * BK, b2, tid, wave);
        SLOT(4) SLOT(5)
        if (pf2) stage_unit(B, bcol, (t + 2) * BK + 32, b2 + 8192, tid, wave);
        SLOT(6) SLOT(7)

        bs = (bs + 1 >= 3) ? 0 : bs + 1;
    }

    // ---- epilogue: scatter via rowmap; C/D col=lane&15, row=(lane>>4)*4+j.
    //      Skipped slots: acc=0 -> stores bias (correct for zero rows). ----
    const int pbase = bm * 256;
#pragma unroll
    for (int n = 0; n < 4; ++n) {
        const size_t col = bcol + wc * 64 + n * 16 + lr;
        const float bs_ = bias[col];
#pragma unroll
        for (int m = 0; m < 8; ++m) {
            const int rl0 = (wr + 2 * m) * 16 + kg * 4;
#pragma unroll
            for (int j = 0; j < 4; ++j) {
                const size_t orow = (size_t)g_rowmap[pbase + rl0 + j];
                C[orow * N + col] = acc[m][n][j] + bs_;
            }
        }
    }
}

extern "C" void kernel_launch(void* const* d_in, const int* in_sizes, int n_in,
                              void* d_out, int out_size, void* d_ws, size_t ws_size,
                              hipStream_t stream) {
    const float* x    = (const float*)d_in[0];   // [T,B,C_IN] = [M,K]
    const float* w    = (const float*)d_in[1];   // [C_OUT,C_IN] = [N,K]
    const float* bias = (const float*)d_in[2];   // [N]
    float* out = (float*)d_out;                  // [M,N]

    unsigned short* Abf = (unsigned short*)d_ws;           // 32 MiB (panel-compacted)
    unsigned short* Bbf = Abf + (size_t)M * K;             // 32 MiB

    reset_k<<<1, 64, 0, stream>>>();
    prep<<<M + 2048, 256, 0, stream>>>(x, w, Abf, Bbf);
    gemm_skip<<<dim3((M / BM) * (N / BN)), 512, 0, stream>>>(Abf, Bbf, bias, out);
}

// Round 17
// 124.826 us; speedup vs baseline: 1.2603x; 1.1562x over previous
//
#include <hip/hip_runtime.h>
#include <hip/hip_bf16.h>

// SparseLinear forward: R16's panel-skip GEMM (92.9us) + streaming prep.
// A is NOT physically compacted: prep_cvt is a pure streaming fp32->bf16
// convert (x->Abf, w->Bbf) with fused per-row zero-detection (wave __any +
// atomicOr); build_map makes a per-panel rowmap (nonzero rows -> front slots)
// + g_front counts; the GEMM stages A through the rowmap using per-lane
// global_load_lds source addresses (LDS layout stays slot-indexed, swizzle
// keyed to slot). Fragment slots >= mfp = ceil(front/16) are skipped via
// wave-uniform guards; skipped slots store 0+bias through the rowmap (exactly
// right for zero rows -> correctness independent of mfp). Lean-sync ledger
// (R14): per tile issue A(t+1), B(t+2); entry vmcnt(4) retains exactly
// B(t+1); prologue rowidx loads are oldest and drained by the first wait.
// A 2-deep + B 3-deep rings (160 KiB), zero-conflict granule-XOR swizzle,
// register-held B, setprio, rowmap-scatter fused-bias epilogue.

typedef __bf16 bf16x8 __attribute__((ext_vector_type(8)));
typedef float f32x4 __attribute__((ext_vector_type(4)));

constexpr int M = 4096;   // T*B
constexpr int N = 4096;   // C_OUT
constexpr int K = 4096;   // C_IN
constexpr int BM = 256, BN = 256, BK = 64;
constexpr int NT = K / BK;          // 64 K-tiles
constexpr int A_BUF = 16384;        // elems per A buffer (2 units: k0,k1)
constexpr int B_BASE = 32768;       // elem offset of B region
constexpr int B_SLOT = 16384;       // elems per B slot (2 units: k0,k1)

__device__ int g_nzflag[M];         // per-row nonzero flag
__device__ int g_front[16];         // per-panel nonzero-row count
__device__ int g_rowmap[M];         // panel slot -> original (absolute) row

__device__ __forceinline__ unsigned short f2bf_rne(float f) {
    unsigned int u = __float_as_uint(f);
    u += 0x7fffu + ((u >> 16) & 1u);   // round-to-nearest-even
    return (unsigned short)(u >> 16);
}

__global__ __launch_bounds__(256) void reset_flags() {
    const int i = blockIdx.x * 256 + threadIdx.x;
    if (i < M) g_nzflag[i] = 0;
}

// Pure streaming convert (x->Abf, w->Bbf) + fused zero-row detection.
// Each wave's 64 lanes cover 512 contiguous elems = 1/8 of one x-row
// (wave base is a multiple of 64 chunks -> row-aligned).
__global__ __launch_bounds__(256) void prep_cvt(
    const float* __restrict__ x, const float* __restrict__ w,
    unsigned short* __restrict__ Abf, unsigned short* __restrict__ Bbf)
{
    const int n8 = (M * K) / 8;
    int idx = blockIdx.x * blockDim.x + threadIdx.x;
    int stride = gridDim.x * blockDim.x;
    for (int i = idx; i < 2 * n8; i += stride) {
        const float* src;
        unsigned short* dst;
        bool isx;
        long b;
        if (i < n8) { b = (long)i * 8;        src = x + b; dst = Abf + b; isx = true; }
        else        { b = (long)(i - n8) * 8; src = w + b; dst = Bbf + b; isx = false; }
        float4 v0 = *(const float4*)(src);
        float4 v1 = *(const float4*)(src + 4);
        ushort4 r0, r1;
        r0.x = f2bf_rne(v0.x); r0.y = f2bf_rne(v0.y);
        r0.z = f2bf_rne(v0.z); r0.w = f2bf_rne(v0.w);
        r1.x = f2bf_rne(v1.x); r1.y = f2bf_rne(v1.y);
        r1.z = f2bf_rne(v1.z); r1.w = f2bf_rne(v1.w);
        *(ushort4*)(dst) = r0;
        *(ushort4*)(dst + 4) = r1;
        if (isx) {
            const bool nz8 = (v0.x != 0.f) | (v0.y != 0.f) | (v0.z != 0.f) |
                             (v0.w != 0.f) | (v1.x != 0.f) | (v1.y != 0.f) |
                             (v1.z != 0.f) | (v1.w != 0.f);
            if (__any(nz8) && (threadIdx.x & 63) == 0) {
                atomicOr(&g_nzflag[i >> 9], 1);   // row = i*8/4096
            }
        }
    }
}

// One block per 256-row panel: nonzero rows -> front slots, zero -> back.
// Slot order within groups is atomic-nondeterministic but the OUTPUT is
// bitwise-deterministic (each row's K-accumulation order is slot-invariant).
__global__ __launch_bounds__(256) void build_map() {
    const int p = blockIdx.x, t = threadIdx.x;
    __shared__ int cnz, cz;
    if (t == 0) { cnz = 0; cz = 0; }
    __syncthreads();
    const int flag = g_nzflag[p * 256 + t];
    const int pos = flag ? atomicAdd(&cnz, 1) : 255 - atomicAdd(&cz, 1);
    g_rowmap[p * 256 + pos] = p * 256 + t;
    __syncthreads();
    if (t == 0) g_front[p] = cnz;
}

// Stage one B k-half unit ([256 rows][32 k], 2 global_load_lds / thread).
// Linear LDS dest; pre-swizzled global source granule: cg ^= (row>>1)&3.
__device__ __forceinline__ void stage_unit(const unsigned short* __restrict__ g,
                                           size_t grow0, int kcol0,
                                           unsigned short* unitbase,
                                           int tid, int wave) {
#pragma unroll
    for (int i = 0; i < 2; ++i) {
        const int row = i * 128 + (tid >> 2);
        const int cg  = (tid & 3) ^ ((row >> 1) & 3);
        const unsigned short* src = g + (grow0 + (size_t)row) * (size_t)K
                                      + (size_t)(kcol0 + cg * 8);
        unsigned short* dst = unitbase + i * 4096 + wave * 512;
        __builtin_amdgcn_global_load_lds(
            (const __attribute__((address_space(1))) void*)src,
            (__attribute__((address_space(3))) void*)dst, 16, 0, 0);
    }
}

// Stage one A k-half unit through the row permutation: LDS slot row is
// i*128+(tid>>2) (swizzle keyed to SLOT); global source row is the
// register-held permuted row (absolute).
__device__ __forceinline__ void stageA_ind(const unsigned short* __restrict__ g,
                                           int rowA0, int rowA1, int kcol0,
                                           unsigned short* unitbase,
                                           int tid, int wave) {
#pragma unroll
    for (int i = 0; i < 2; ++i) {
        const int slotrow = i * 128 + (tid >> 2);
        const int srow    = i ? rowA1 : rowA0;
        const int cg  = (tid & 3) ^ ((slotrow >> 1) & 3);
        const unsigned short* src = g + (size_t)srow * (size_t)K
                                      + (size_t)(kcol0 + cg * 8);
        unsigned short* dst = unitbase + i * 4096 + wave * 512;
        __builtin_amdgcn_global_load_lds(
            (const __attribute__((address_space(1))) void*)src,
            (__attribute__((address_space(3))) void*)dst, 16, 0, 0);
    }
}

// One fragment slot S (frag = wr + 2*S): 2 A-reads (k0,k1) x held b[4][2],
// 8 MFMA. Guard is wave-uniform; skipped slots keep acc=0.
#define SLOT(S)                                                                \
    if (wr + 2 * (S) < mfp) {                                                  \
        bf16x8 ak0 = *(const bf16x8*)(pA0 + (S) * 1024);                       \
        bf16x8 ak1 = *(const bf16x8*)(pA1 + (S) * 1024);                       \
        __builtin_amdgcn_s_setprio(1);                                         \
        _Pragma("unroll")                                                      \
        for (int n = 0; n < 4; ++n)                                            \
            acc[S][n] = __builtin_amdgcn_mfma_f32_16x16x32_bf16(               \
                ak0, b[n][0], acc[S][n], 0, 0, 0);                             \
        _Pragma("unroll")                                                      \
        for (int n = 0; n < 4; ++n)                                            \
            acc[S][n] = __builtin_amdgcn_mfma_f32_16x16x32_bf16(               \
                ak1, b[n][1], acc[S][n], 0, 0, 0);                             \
        __builtin_amdgcn_s_setprio(0);                                         \
    }

__global__ __launch_bounds__(512, 2) void gemm_skip2(
    const unsigned short* __restrict__ A,   // [M][K] bf16 (original order)
    const unsigned short* __restrict__ B,   // [N][K] bf16
    const float* __restrict__ bias,         // [N]
    float* __restrict__ C)                  // [M][N] fp32 (rowmap scatter)
{
    __shared__ unsigned short lds[81920];   // 160 KiB: A 2-deep + B 3-deep

    // XCD-aware bijective swizzle: 256 wgs, 256 % 8 == 0
    const int wg = blockIdx.x;
    const int s  = ((wg & 7) << 5) | (wg >> 3);
    const int bm = s >> 4, bn = s & 15;
    const size_t bcol = (size_t)bn * BN;
    const int pbase = bm * 256;

    const int mfp = (*(volatile int*)&g_front[bm] + 15) >> 4;   // active frags

    const int tid  = threadIdx.x;
    const int wave = tid >> 6;
    const int lane = tid & 63;
    const int wr = wave >> 2;       // 0..1 : owns frags wr+2m (interleaved)
    const int wc = wave & 3;        // 0..3  (4 N-waves, 64 cols each)
    const int lr = lane & 15;       // fragment row-in-16
    const int kg = lane >> 4;       // k-group 0..3

    const int a_row0 = wr * 16 + lr;          // frag wr base rows (slot space)
    const int b_row0 = wc * 64 + lr;
    const int aoff = a_row0 * 32 + ((kg ^ ((a_row0 >> 1) & 3)) << 3);
    const int boff = b_row0 * 32 + ((kg ^ ((b_row0 >> 1) & 3)) << 3);

    // Per-thread A staging source rows (loaded BEFORE the staged-load ledger
    // starts; these 2 loads are the oldest and drained by the first vmcnt(4)).
    const int rowA0 = g_rowmap[pbase + (tid >> 2)];
    const int rowA1 = g_rowmap[pbase + 128 + (tid >> 2)];

    f32x4 acc[8][4];
#pragma unroll
    for (int m = 0; m < 8; ++m)
#pragma unroll
        for (int n = 0; n < 4; ++n)
            acc[m][n] = (f32x4){0.f, 0.f, 0.f, 0.f};

    // ---- prologue: B(0), A(0), B(1) = 12 loads (B(1) newest) ----
    stage_unit(B, bcol, 0,       lds + B_BASE, tid, wave);
    stage_unit(B, bcol, 32,      lds + B_BASE + 8192, tid, wave);
    stageA_ind(A, rowA0, rowA1, 0,  lds, tid, wave);
    stageA_ind(A, rowA0, rowA1, 32, lds + 8192, tid, wave);
    stage_unit(B, bcol, BK,      lds + B_BASE + B_SLOT, tid, wave);
    stage_unit(B, bcol, BK + 32, lds + B_BASE + B_SLOT + 8192, tid, wave);

    int bs = 0;   // B ring slot of tile t
    for (int t = 0; t < NT; ++t) {
        const bool pf1 = (t + 1) < NT;
        const bool pf2 = (t + 2) < NT;

        // Entry wait: A(t)+B(t) landed; B(t+1)'s 4 loads stay in flight.
        if (pf1) { asm volatile("s_waitcnt vmcnt(4)" ::: "memory"); }
        else     { asm volatile("s_waitcnt vmcnt(0)" ::: "memory"); }
        __builtin_amdgcn_s_barrier();

        unsigned short* aB = lds + (t & 1) * A_BUF;
        unsigned short* ao = lds + ((t & 1) ^ 1) * A_BUF;    // A stage target
        unsigned short* bb = lds + B_BASE + bs * B_SLOT;
        const int bs2 = (bs + 2 >= 3) ? bs - 1 : bs + 2;     // (t+2)%3
        unsigned short* b2 = lds + B_BASE + bs2 * B_SLOT;    // B stage target

        const unsigned short* pA0 = aB + aoff;
        const unsigned short* pA1 = aB + 8192 + aoff;

        // ===== B-frags for whole tile (register-held) =====
        bf16x8 b[4][2];
#pragma unroll
        for (int n = 0; n < 4; ++n) {
            b[n][0] = *(const bf16x8*)(bb + boff + n * 512);
            b[n][1] = *(const bf16x8*)(bb + 8192 + boff + n * 512);
        }

        if (pf1) stageA_ind(A, rowA0, rowA1, (t + 1) * BK, ao, tid, wave);
        SLOT(0) SLOT(1)
        if (pf1) stageA_ind(A, rowA0, rowA1, (t + 1) * BK + 32, ao + 8192, tid, wave);
        SLOT(2) SLOT(3)
        if (pf2) stage_unit(B, bcol, (t + 2) * BK, b2, tid, wave);
        SLOT(4) SLOT(5)
        if (pf2) stage_unit(B, bcol, (t + 2) * BK + 32, b2 + 8192, tid, wave);
        SLOT(6) SLOT(7)

        bs = (bs + 1 >= 3) ? 0 : bs + 1;
    }

    // ---- epilogue: scatter via rowmap; C/D col=lane&15, row=(lane>>4)*4+j.
    //      Skipped slots: acc=0 -> stores bias (correct for zero rows). ----
#pragma unroll
    for (int n = 0; n < 4; ++n) {
        const size_t col = bcol + wc * 64 + n * 16 + lr;
        const float bs_ = bias[col];
#pragma unroll
        for (int m = 0; m < 8; ++m) {
            const int rl0 = (wr + 2 * m) * 16 + kg * 4;
#pragma unroll
            for (int j = 0; j < 4; ++j) {
                const size_t orow = (size_t)g_rowmap[pbase + rl0 + j];
                C[orow * N + col] = acc[m][n][j] + bs_;
            }
        }
    }
}

extern "C" void kernel_launch(void* const* d_in, const int* in_sizes, int n_in,
                              void* d_out, int out_size, void* d_ws, size_t ws_size,
                              hipStream_t stream) {
    const float* x    = (const float*)d_in[0];   // [T,B,C_IN] = [M,K]
    const float* w    = (const float*)d_in[1];   // [C_OUT,C_IN] = [N,K]
    const float* bias = (const float*)d_in[2];   // [N]
    float* out = (float*)d_out;                  // [M,N]

    unsigned short* Abf = (unsigned short*)d_ws;           // 32 MiB
    unsigned short* Bbf = Abf + (size_t)M * K;             // 32 MiB

    reset_flags<<<16, 256, 0, stream>>>();
    prep_cvt<<<4096, 256, 0, stream>>>(x, w, Abf, Bbf);
    build_map<<<16, 256, 0, stream>>>();
    gemm_skip2<<<dim3((M / BM) * (N / BN)), 512, 0, stream>>>(Abf, Bbf, bias, out);
}